// Round 2
// baseline (83.155 us; speedup 1.0000x reference)
//
#include <hip/hip_runtime.h>
#include <math.h>

#define BB 4
#define LL 1024
#define DD 128
#define UU 32
#define WW 64
#define HALF 32

// ---------------- Kernel A: q = x.Wt + bh ; kT[b,u,l] = x.Wx ----------------
// 1024 blocks x 256 thr; each 64-lane wave handles one row; lanes<32 -> q,
// lanes>=32 -> k (transposed store so attn's k reads are lane-coalesced).
__global__ __launch_bounds__(256) void qk_kernel(
    const float* __restrict__ x, const float* __restrict__ Wt,
    const float* __restrict__ Wx, const float* __restrict__ bh,
    float* __restrict__ q, float* __restrict__ kT)
{
    __shared__ float xs[4][DD];
    const int tid = threadIdx.x;
    const int w = tid >> 6, lane = tid & 63;
    const int row = blockIdx.x * 4 + w;            // row = b*LL + l
    const float* xr = x + (size_t)row * DD;
    if (lane < 32) ((float4*)xs[w])[lane] = ((const float4*)xr)[lane];
    __syncthreads();
    const int u = lane & 31;
    const bool isQ = (lane < 32);
    const float* Wm = isQ ? Wt : Wx;
    float acc = 0.f;
    #pragma unroll 8
    for (int d = 0; d < DD; ++d)
        acc = fmaf(xs[w][d], Wm[d * UU + u], acc);
    if (isQ) {
        q[(size_t)row * UU + u] = acc + bh[u];
    } else {
        const int b = row >> 10, l = row & (LL - 1);
        kT[((size_t)(b * UU + u)) * LL + l] = acc;
    }
}

// ---------------- Kernel B: windowed attention, LDS-tiled ----------------
// 512 blocks x 256 thr. Block handles 8 query rows; stages the 71-row x
// window union (36 KB), the kT slice (9 KB) and q (1 KB) into LDS once.
#define RPB 8
#define XR  71            // RPB + WW - 1
#define XRP 72            // padded row count

__global__ __launch_bounds__(256) void attn_kernel(
    const float* __restrict__ x, const float* __restrict__ q,
    const float* __restrict__ kT, const float* __restrict__ Wa,
    float* __restrict__ out)
{
    __shared__ float xs[XRP][DD];       // 36 KB, PV reads: row-uniform, lane-d float2 -> conflict-free
    __shared__ float kts[UU][XRP];      // 9 KB, e reads: uniform u, consecutive lanes -> conflict-free
    __shared__ float qs[RPB][UU];       // 1 KB
    __shared__ float was[UU];
    __shared__ float as[4][2][WW];      // per-wave, per-sub-row attention weights

    const int tid = threadIdx.x;
    const int blk = blockIdx.x;         // 512 = BB * (LL/RPB)
    const int b  = blk >> 7;
    const int i0 = (blk & 127) * RPB;
    const int j0 = i0 - HALF;           // window start (may be <0)

    const float* xb = x + (size_t)b * LL * DD;

    // stage x rows j0 .. j0+70 (clamped; clamped rows only feed a==0 slots)
    {
        const float4* xb4 = (const float4*)xb;
        for (int s = tid; s < XRP * (DD / 4); s += 256) {
            const int r = s >> 5;                 // DD/4 == 32
            const int c = s & 31;
            int jg = j0 + r; jg = min(max(jg, 0), LL - 1);
            ((float4*)xs)[s] = xb4[jg * (DD / 4) + c];
        }
    }
    // stage kT slice [32][71]
    {
        const float* kb = kT + (size_t)b * UU * LL;
        for (int s = tid; s < UU * XRP; s += 256) {
            const int u = s / XRP;
            const int r = s - u * XRP;
            int jg = j0 + r; jg = min(max(jg, 0), LL - 1);
            kts[u][r] = kb[(size_t)u * LL + jg];
        }
    }
    // stage q for the block's 8 rows (exactly 256 values) and Wa
    ((float*)qs)[tid] = q[((size_t)(b * LL + i0)) * UU + tid];
    if (tid < UU) was[tid] = Wa[tid];
    __syncthreads();

    const int w = tid >> 6, lane = tid & 63;

    #pragma unroll
    for (int rr = 0; rr < 2; ++rr) {
        const int ir = w * 2 + rr;              // 0..7 within block
        const int i  = i0 + ir;                 // query row
        const int j  = i - HALF + lane;         // this lane's window position
        const bool valid = (j >= 0) && (j < LL);

        // e_j = sum_u Wa_u * tanh(q_u + k_{j,u})
        float acc = 0.f;
        #pragma unroll
        for (int u = 0; u < UU; ++u) {
            const float t = qs[ir][u] + kts[u][ir + lane];
            // tanh(t) = 1 - 2/(exp(2t)+1)
            const float ex = __expf(2.f * t);
            acc = fmaf(was[u], fmaf(-2.f, __builtin_amdgcn_rcpf(ex + 1.f), 1.f), acc);
        }
        const float e = valid ? acc : -INFINITY;

        // wave softmax over the 64-slot window
        float m = e;
        #pragma unroll
        for (int off = 32; off > 0; off >>= 1)
            m = fmaxf(m, __shfl_xor(m, off));
        const float p = valid ? __expf(e - m) : 0.f;
        float s = p;
        #pragma unroll
        for (int off = 32; off > 0; off >>= 1)
            s += __shfl_xor(s, off);
        const float a = p * __builtin_amdgcn_rcpf(s + 1e-7f);
        as[w][rr][lane] = a;

        // PV: v_i = sum_l a_l * x[j0+ir+l, :]; lane covers d = 2*lane, 2*lane+1
        float v0 = 0.f, v1 = 0.f;
        #pragma unroll 8
        for (int l = 0; l < WW; ++l) {
            const float al = as[w][rr][l];
            const float2 xv = ((const float2*)xs[ir + l])[lane];
            v0 = fmaf(al, xv.x, v0);
            v1 = fmaf(al, xv.y, v1);
        }
        float2 o; o.x = v0; o.y = v1;
        ((float2*)(out + ((size_t)(b * LL + i)) * DD))[lane] = o;
    }
}

extern "C" void kernel_launch(void* const* d_in, const int* in_sizes, int n_in,
                              void* d_out, int out_size, void* d_ws, size_t ws_size,
                              hipStream_t stream) {
    const float* x  = (const float*)d_in[0];
    const float* Wt = (const float*)d_in[1];
    const float* Wx = (const float*)d_in[2];
    const float* bh = (const float*)d_in[3];
    const float* Wa = (const float*)d_in[4];
    // d_in[5] = ba : uniform shift of e, cancels exactly in softmax -> unused
    float* out = (float*)d_out;

    float* q  = (float*)d_ws;                       // [B,L,U]  512 KB
    float* kT = q + (size_t)BB * LL * UU;           // [B,U,L]  512 KB

    qk_kernel<<<BB * LL / 4, 256, 0, stream>>>(x, Wt, Wx, bh, q, kT);
    attn_kernel<<<BB * (LL / RPB), 256, 0, stream>>>(x, q, kT, Wa, out);
}

// Round 3
// 81.178 us; speedup vs baseline: 1.0244x; 1.0244x over previous
//
#include <hip/hip_runtime.h>
#include <math.h>

#define BB 4
#define LL 1024
#define DD 128
#define UU 32
#define WW 64
#define HALF 32
#define RPB 8
#define XR  72          // staged window rows (71 used + 1 pad)

// One block = 8 query rows. Stages x window + Wx into LDS, computes k/q
// GEMVs in-block (no workspace, no second kernel), then e/softmax/PV.
__global__ __launch_bounds__(256) void fused_attn(
    const float* __restrict__ x, const float* __restrict__ Wt,
    const float* __restrict__ Wx, const float* __restrict__ bh,
    const float* __restrict__ Wa, float* __restrict__ out)
{
    __shared__ float xs[XR][DD];     // 36 KB  x window rows j0..j0+71 (clamped)
    __shared__ float wxs[DD][UU];    // 16 KB  Wx
    __shared__ float kts[UU][XR];    //  9 KB  k^T slice
    __shared__ float qs[RPB][UU];    //  1 KB
    __shared__ float was[UU];
    __shared__ float as[4][2][WW];   //  2 KB  per-wave attention weights

    const int tid = threadIdx.x;
    const int blk = blockIdx.x;      // 512 = BB * (LL/RPB)
    const int b   = blk >> 7;
    const int i0  = (blk & 127) * RPB;
    const int j0  = i0 - HALF;

    const float* xb = x + (size_t)b * LL * DD;

    // ---- stage x window (72 rows, index-clamped; clamped rows get a==0) ----
    {
        const float4* xb4 = (const float4*)xb;
        float4* xs4 = (float4*)xs;
        #pragma unroll
        for (int t = 0; t < 9; ++t) {             // 72*(128/4)/256 = 9
            const int s = tid + t * 256;
            const int r = s >> 5, c = s & 31;
            int jg = j0 + r; jg = min(max(jg, 0), LL - 1);
            xs4[s] = xb4[jg * (DD / 4) + c];
        }
    }
    // ---- stage Wx ----
    {
        const float4* w4 = (const float4*)Wx;
        float4* wx4 = (float4*)wxs;
        #pragma unroll
        for (int t = 0; t < 4; ++t)               // 4096/4/256 = 4
            wx4[tid + t * 256] = w4[tid + t * 256];
    }
    if (tid < UU) was[tid] = Wa[tid];
    __syncthreads();

    const int r0 = tid >> 5, u = tid & 31;        // r0 in 0..7

    // ---- k GEMV: thread owns rows r0+8k (k=0..8), one u column ----
    {
        float acc[9];
        #pragma unroll
        for (int k = 0; k < 9; ++k) acc[k] = 0.f;
        #pragma unroll 4
        for (int d4 = 0; d4 < DD / 4; ++d4) {
            const float w0 = wxs[4 * d4 + 0][u];
            const float w1 = wxs[4 * d4 + 1][u];
            const float w2 = wxs[4 * d4 + 2][u];
            const float w3 = wxs[4 * d4 + 3][u];
            #pragma unroll
            for (int k = 0; k < 9; ++k) {
                const float4 xv = ((const float4*)xs[r0 + 8 * k])[d4];  // broadcast b128
                acc[k] = fmaf(xv.x, w0, fmaf(xv.y, w1,
                         fmaf(xv.z, w2, fmaf(xv.w, w3, acc[k]))));
            }
        }
        #pragma unroll
        for (int k = 0; k < 9; ++k) kts[u][r0 + 8 * k] = acc[k];
    }
    // ---- q GEMV: one output per thread (row r0, unit u), Wt via L1 ----
    {
        float acc = bh[u];
        #pragma unroll 4
        for (int d4 = 0; d4 < DD / 4; ++d4) {
            const float4 xv = ((const float4*)xs[HALF + r0])[d4];
            acc = fmaf(xv.x, Wt[(4 * d4 + 0) * UU + u],
                  fmaf(xv.y, Wt[(4 * d4 + 1) * UU + u],
                  fmaf(xv.z, Wt[(4 * d4 + 2) * UU + u],
                  fmaf(xv.w, Wt[(4 * d4 + 3) * UU + u], acc))));
        }
        qs[r0][u] = acc;
    }
    __syncthreads();

    // ---- e / softmax / PV: one wave per 2 query rows ----
    const int w = tid >> 6, lane = tid & 63;
    #pragma unroll
    for (int rr = 0; rr < 2; ++rr) {
        const int ir = w * 2 + rr;               // 0..7
        const int i  = i0 + ir;
        const int j  = i - HALF + lane;
        const bool valid = (j >= 0) && (j < LL);

        float acc = 0.f;
        #pragma unroll
        for (int uu = 0; uu < UU; ++uu) {
            const float t = qs[ir][uu] + kts[uu][ir + lane];
            const float ex = __expf(2.f * t);    // tanh = 1 - 2/(e^{2t}+1)
            acc = fmaf(was[uu], fmaf(-2.f, __builtin_amdgcn_rcpf(ex + 1.f), 1.f), acc);
        }
        const float e = valid ? acc : -INFINITY;

        float m = e;
        #pragma unroll
        for (int off = 32; off > 0; off >>= 1)
            m = fmaxf(m, __shfl_xor(m, off));
        const float p = valid ? __expf(e - m) : 0.f;
        float s = p;
        #pragma unroll
        for (int off = 32; off > 0; off >>= 1)
            s += __shfl_xor(s, off);
        const float a = p * __builtin_amdgcn_rcpf(s + 1e-7f);
        as[w][rr][lane] = a;

        float v0 = 0.f, v1 = 0.f;
        #pragma unroll 8
        for (int l = 0; l < WW; ++l) {
            const float al = as[w][rr][l];
            const float2 xv = ((const float2*)xs[ir + l])[lane];
            v0 = fmaf(al, xv.x, v0);
            v1 = fmaf(al, xv.y, v1);
        }
        float2 o; o.x = v0; o.y = v1;
        ((float2*)(out + ((size_t)(b * LL + i)) * DD))[lane] = o;
    }
}

extern "C" void kernel_launch(void* const* d_in, const int* in_sizes, int n_in,
                              void* d_out, int out_size, void* d_ws, size_t ws_size,
                              hipStream_t stream) {
    const float* x  = (const float*)d_in[0];
    const float* Wt = (const float*)d_in[1];
    const float* Wx = (const float*)d_in[2];
    const float* bh = (const float*)d_in[3];
    const float* Wa = (const float*)d_in[4];
    // d_in[5] = ba : uniform shift of e, cancels exactly in softmax -> unused
    float* out = (float*)d_out;

    fused_attn<<<BB * (LL / RPB), 256, 0, stream>>>(x, Wt, Wx, bh, Wa, out);
}